// Round 23
// baseline (131.498 us; speedup 1.0000x reference)
//
#include <hip/hip_runtime.h>
#include <hip/hip_bf16.h>

typedef __attribute__((ext_vector_type(4))) float f32x4;
typedef __attribute__((ext_vector_type(8))) short bf16x8;

__device__ __forceinline__ unsigned short f2bf(float f) {
  union { float f; unsigned int u; } v; v.f = f;
  unsigned int u = v.u;
  unsigned int r = (u + 0x7FFFu + ((u >> 16) & 1u)) >> 16;  // RNE
  return (unsigned short)r;
}

// ---------------- prep: pack W1(rows 4..260) and W2 into MFMA-B fragment order ----
__global__ void pack_w_kernel(const float* __restrict__ W1, const float* __restrict__ W2,
                              unsigned short* __restrict__ Bp1, unsigned short* __restrict__ Bp2) {
  int p = blockIdx.x * 256 + threadIdx.x;
  if (p < 32768) {                      // 256x128 for layer 1 (W1 rows 4..260)
    int j = p & 7, n = (p >> 3) & 127, kb = p >> 10;
    Bp1[p] = f2bf(W1[(4 + kb * 8 + j) * 128 + n]);
  } else if (p < 49152) {               // 128x128 for layer 2
    int q = p - 32768;
    int j = q & 7, n = (q >> 3) & 127, kb = q >> 10;
    Bp2[q] = f2bf(W2[(kb * 8 + j) * 128 + n]);
  }
}

// ---------------- prep: x fp32 -> bf16 ----------------
__global__ void convert_x_kernel(const float* __restrict__ x, unsigned short* __restrict__ xb, int n8) {
  int i = blockIdx.x * blockDim.x + threadIdx.x;
  if (i >= n8) return;
  const float4* s = (const float4*)x + (size_t)i * 2;
  float4 a = s[0], b = s[1];
  unsigned short h[8] = {f2bf(a.x), f2bf(a.y), f2bf(a.z), f2bf(a.w),
                         f2bf(b.x), f2bf(b.y), f2bf(b.z), f2bf(b.w)};
  int4 pk; __builtin_memcpy(&pk, h, 16);
  ((int4*)xb)[i] = pk;
}

constexpr int BM = 64;

// ---------------- main fused kernel: one 64-edge tile per block, 3 blocks/CU ----
// R16 VERBATIM — the measured optimum (131.3-131.8 us, reproduced twice) across
// 22 rounds of A/B experiments:
// - 10000 blocks x 256 threads, one 64-edge tile each, 3 blocks/CU (49 KB LDS).
//   The ONLY clean-traffic configuration: 4/CU, 2-tile blocks, 8-wave blocks, and
//   persistent grids all amplify WRITE 2-4x (R5/R6/R7/R14/R17/R18/R19).
// - Staged normal-load bf16 gather (separate convert_x pass beats fused fp32
//   gather: R9/R20).
// - Hoisted B-fragments above the gather barrier (R2's latency win).
// - NT full-line epilogue via padded LDS restage: 64 lanes x 16 B contiguous per
//   wave-instruction -> write-combines to HBM, no L2 dirty lines (R16's -16%).
//   Partial-line NT is catastrophic (R3); sc1-flag asm variant miscomputed (R22).
__global__ __launch_bounds__(256, 3)
void edge_nt(const unsigned short* __restrict__ xb,
             const float* __restrict__ ea, const int* __restrict__ eidx,
             const float* __restrict__ W1, const float* __restrict__ b1,
             const float* __restrict__ b2,
             const unsigned short* __restrict__ Bp1, const unsigned short* __restrict__ Bp2,
             float* __restrict__ outp, int E) {
  __shared__ int4 AldsV[2112];   // 33 KB: A-tile [64][256] bf16 swizzled; reused as f32 out-stage [64][132]
  __shared__ int4 HldsV[1024];   // 16 KB  h [64][128] bf16, XOR-swizzled
  __shared__ float ealds[256];   // 64 edges x 4 attrs

  char* Alds = (char*)AldsV;
  float* Olds = (float*)AldsV;   // overlay (valid after the pre-layer-2 barrier)
  char* Hlds = (char*)HldsV;

  const int tid  = threadIdx.x;
  const int lane = tid & 63;
  const int wq   = lane >> 4;
  const int l16  = lane & 15;
  const int wave = tid >> 6;
  const int g    = tid & 15;
  const int s0   = tid >> 4;
  const int eb   = blockIdx.x * BM;

  // ---- issue independent loads first: edge_attr, eidx ----
  ealds[tid] = ea[eb * 4 + tid];

  int idxv[8];
  #pragma unroll
  for (int it = 0; it < 8; ++it) {
    int seg = it * 16 + s0;
    idxv[it] = eidx[(seg & 1) * E + eb + (seg >> 1)];
  }

  // ---- gather loads: normal (L2-allocating) int4 loads into VGPRs ----
  int4 gv[8];
  #pragma unroll
  for (int it = 0; it < 8; ++it)
    gv[it] = *(const int4*)(xb + (size_t)idxv[it] * 128 + g * 8);

  const int c0 = wave * 32 + l16;
  const int c1 = c0 + 16;

  // ---- hoisted scalars + layer-1 B fragments (latency overlaps gather) ----
  const float bias0 = b1[c0], bias1 = b1[c1];
  const float w00 = W1[c0],       w01 = W1[128 + c0], w02 = W1[256 + c0], w03 = W1[384 + c0];
  const float w10 = W1[c1],       w11 = W1[128 + c1], w12 = W1[256 + c1], w13 = W1[384 + c1];
  const float bias20 = b2[c0], bias21 = b2[c1];

  bf16x8 bf1r[8][2];
  #pragma unroll
  for (int ks = 0; ks < 8; ++ks) {
    int kb = ks * 4 + wq;
    bf1r[ks][0] = __builtin_bit_cast(bf16x8, *(const int4*)(Bp1 + ((size_t)kb * 128 + c0) * 8));
    bf1r[ks][1] = __builtin_bit_cast(bf16x8, *(const int4*)(Bp1 + ((size_t)kb * 128 + c1) * 8));
  }

  // ---- stage gather into LDS (XOR-swizzled dest, b128 writes) ----
  #pragma unroll
  for (int it = 0; it < 8; ++it) {
    int seg = it * 16 + s0;
    int r = seg >> 1, half = seg & 1;
    int lofs = (r * 512 + half * 256 + g * 16) ^ ((r & 7) << 4);
    *(int4*)(Alds + lofs) = gv[it];
  }
  __syncthreads();

  // ---- layer 1 accumulator init: b1 + edge_attr x W1[0:4] in fp32 ----
  f32x4 acc[4][2];
  #pragma unroll
  for (int mf = 0; mf < 4; ++mf)
    #pragma unroll
    for (int rg = 0; rg < 4; ++rg) {
      int r = mf * 16 + wq * 4 + rg;
      float e0 = ealds[r * 4 + 0], e1 = ealds[r * 4 + 1];
      float e2 = ealds[r * 4 + 2], e3 = ealds[r * 4 + 3];
      acc[mf][0][rg] = bias0 + e0 * w00 + e1 * w01 + e2 * w02 + e3 * w03;
      acc[mf][1][rg] = bias1 + e0 * w10 + e1 * w11 + e2 * w12 + e3 * w13;
    }

  // ---- layer 1 MFMA: K = 256 (sender 128 | receiver 128), B from registers ----
  #pragma unroll
  for (int ks = 0; ks < 8; ++ks) {
    #pragma unroll
    for (int mf = 0; mf < 4; ++mf) {
      int r = mf * 16 + l16;
      int lofs = (r * 512 + ks * 64 + wq * 16) ^ ((r & 7) << 4);
      bf16x8 av = __builtin_bit_cast(bf16x8, *(const int4*)(Alds + lofs));
      acc[mf][0] = __builtin_amdgcn_mfma_f32_16x16x32_bf16(av, bf1r[ks][0], acc[mf][0], 0, 0, 0);
      acc[mf][1] = __builtin_amdgcn_mfma_f32_16x16x32_bf16(av, bf1r[ks][1], acc[mf][1], 0, 0, 0);
    }
  }

  // ---- layer-2 B fragments: issue now, latency hides under H-write + barrier ----
  bf16x8 bf2r[4][2];
  #pragma unroll
  for (int ks = 0; ks < 4; ++ks) {
    int kb = ks * 4 + wq;
    bf2r[ks][0] = __builtin_bit_cast(bf16x8, *(const int4*)(Bp2 + ((size_t)kb * 128 + c0) * 8));
    bf2r[ks][1] = __builtin_bit_cast(bf16x8, *(const int4*)(Bp2 + ((size_t)kb * 128 + c1) * 8));
  }

  // ---- ReLU + h -> LDS (bf16, swizzled) ----
  #pragma unroll
  for (int mf = 0; mf < 4; ++mf)
    #pragma unroll
    for (int nf = 0; nf < 2; ++nf) {
      int c = wave * 32 + nf * 16 + l16;
      #pragma unroll
      for (int rg = 0; rg < 4; ++rg) {
        int r = mf * 16 + wq * 4 + rg;
        float v = fmaxf(acc[mf][nf][rg], 0.0f);
        int lofs = (r * 256 + c * 2) ^ ((r & 7) << 4);
        *(unsigned short*)(Hlds + lofs) = f2bf(v);
      }
    }
  __syncthreads();   // after this barrier ALL waves are done reading Alds -> Olds overlay safe

  // ---- layer 2: K = 128 ----
  f32x4 acc2[4][2];
  #pragma unroll
  for (int mf = 0; mf < 4; ++mf) {
    acc2[mf][0] = (f32x4){bias20, bias20, bias20, bias20};
    acc2[mf][1] = (f32x4){bias21, bias21, bias21, bias21};
  }
  #pragma unroll
  for (int ks = 0; ks < 4; ++ks) {
    #pragma unroll
    for (int mf = 0; mf < 4; ++mf) {
      int r = mf * 16 + l16;
      int lofs = (r * 256 + ks * 64 + wq * 16) ^ ((r & 7) << 4);
      bf16x8 av = __builtin_bit_cast(bf16x8, *(const int4*)(Hlds + lofs));
      acc2[mf][0] = __builtin_amdgcn_mfma_f32_16x16x32_bf16(av, bf2r[ks][0], acc2[mf][0], 0, 0, 0);
      acc2[mf][1] = __builtin_amdgcn_mfma_f32_16x16x32_bf16(av, bf2r[ks][1], acc2[mf][1], 0, 0, 0);
    }
  }

  // ---- stage acc2 -> LDS f32 [64][132] (padded stride kills write conflicts) ----
  #pragma unroll
  for (int mf = 0; mf < 4; ++mf)
    #pragma unroll
    for (int nf = 0; nf < 2; ++nf) {
      int c = wave * 32 + nf * 16 + l16;
      #pragma unroll
      for (int rg = 0; rg < 4; ++rg) {
        int r = mf * 16 + wq * 4 + rg;
        Olds[r * 132 + c] = acc2[mf][nf][rg];
      }
    }
  __syncthreads();

  // ---- epilogue: contiguous NT full-line stores (1024 B per wave-instruction) ----
  float* outbase = outp + (size_t)eb * 128;
  #pragma unroll
  for (int p = 0; p < 8; ++p) {
    int i = p * 256 + tid;            // float4 index within the 64x128 tile
    int r = i >> 5, c4 = i & 31;      // 32 float4 per row
    f32x4 v = *(const f32x4*)(Olds + r * 132 + c4 * 4);
    __builtin_nontemporal_store(v, (f32x4*)(outbase + i * 4));
  }
}

// ---------------- fallback (fp32 gather, fused, 3/CU) for small ws ----------------
__global__ __launch_bounds__(256, 3)
void edge_fused_f32(const float* __restrict__ xf,
                    const float* __restrict__ ea, const int* __restrict__ eidx,
                    const float* __restrict__ W1, const float* __restrict__ b1,
                    const float* __restrict__ b2,
                    const unsigned short* __restrict__ Bp1, const unsigned short* __restrict__ Bp2,
                    float* __restrict__ outp, int E) {
  __shared__ int4 AldsV[2048];
  __shared__ int4 HldsV[1024];
  __shared__ float ealds[256];
  char* Alds = (char*)AldsV;
  char* Hlds = (char*)HldsV;

  const int tid  = threadIdx.x;
  const int lane = tid & 63;
  const int wq   = lane >> 4;
  const int l16  = lane & 15;
  const int wave = tid >> 6;
  const int g    = tid & 15;
  const int s0   = tid >> 4;
  const int eb   = blockIdx.x * BM;

  ealds[tid] = ea[eb * 4 + tid];

  int idxv[8];
  #pragma unroll
  for (int it = 0; it < 8; ++it) {
    int seg = it * 16 + s0;
    idxv[it] = eidx[(seg & 1) * E + eb + (seg >> 1)];
  }

  float4 ga[8], gb[8];
  #pragma unroll
  for (int it = 0; it < 8; ++it) {
    const float* src = xf + (size_t)idxv[it] * 128 + g * 8;
    ga[it] = *(const float4*)src;
    gb[it] = *(const float4*)(src + 4);
  }

  const int c0 = wave * 32 + l16;
  const int c1 = c0 + 16;
  const float bias0 = b1[c0], bias1 = b1[c1];
  const float w00 = W1[c0],       w01 = W1[128 + c0], w02 = W1[256 + c0], w03 = W1[384 + c0];
  const float w10 = W1[c1],       w11 = W1[128 + c1], w12 = W1[256 + c1], w13 = W1[384 + c1];
  const float bias20 = b2[c0], bias21 = b2[c1];

  bf16x8 bf1r[8][2];
  #pragma unroll
  for (int ks = 0; ks < 8; ++ks) {
    int kb = ks * 4 + wq;
    bf1r[ks][0] = __builtin_bit_cast(bf16x8, *(const int4*)(Bp1 + ((size_t)kb * 128 + c0) * 8));
    bf1r[ks][1] = __builtin_bit_cast(bf16x8, *(const int4*)(Bp1 + ((size_t)kb * 128 + c1) * 8));
  }

  #pragma unroll
  for (int it = 0; it < 8; ++it) {
    int seg = it * 16 + s0;
    int r = seg >> 1, half = seg & 1;
    int lofs = (r * 512 + half * 256 + g * 16) ^ ((r & 7) << 4);
    unsigned short h[8] = {f2bf(ga[it].x), f2bf(ga[it].y), f2bf(ga[it].z), f2bf(ga[it].w),
                           f2bf(gb[it].x), f2bf(gb[it].y), f2bf(gb[it].z), f2bf(gb[it].w)};
    int4 pk; __builtin_memcpy(&pk, h, 16);
    *(int4*)(Alds + lofs) = pk;
  }
  __syncthreads();

  f32x4 acc[4][2];
  #pragma unroll
  for (int mf = 0; mf < 4; ++mf)
    #pragma unroll
    for (int rg = 0; rg < 4; ++rg) {
      int r = mf * 16 + wq * 4 + rg;
      float e0 = ealds[r * 4 + 0], e1 = ealds[r * 4 + 1];
      float e2 = ealds[r * 4 + 2], e3 = ealds[r * 4 + 3];
      acc[mf][0][rg] = bias0 + e0 * w00 + e1 * w01 + e2 * w02 + e3 * w03;
      acc[mf][1][rg] = bias1 + e0 * w10 + e1 * w11 + e2 * w12 + e3 * w13;
    }

  #pragma unroll
  for (int ks = 0; ks < 8; ++ks)
    #pragma unroll
    for (int mf = 0; mf < 4; ++mf) {
      int r = mf * 16 + l16;
      int lofs = (r * 512 + ks * 64 + wq * 16) ^ ((r & 7) << 4);
      bf16x8 av = __builtin_bit_cast(bf16x8, *(const int4*)(Alds + lofs));
      acc[mf][0] = __builtin_amdgcn_mfma_f32_16x16x32_bf16(av, bf1r[ks][0], acc[mf][0], 0, 0, 0);
      acc[mf][1] = __builtin_amdgcn_mfma_f32_16x16x32_bf16(av, bf1r[ks][1], acc[mf][1], 0, 0, 0);
    }

  bf16x8 bf2r[4][2];
  #pragma unroll
  for (int ks = 0; ks < 4; ++ks) {
    int kb = ks * 4 + wq;
    bf2r[ks][0] = __builtin_bit_cast(bf16x8, *(const int4*)(Bp2 + ((size_t)kb * 128 + c0) * 8));
    bf2r[ks][1] = __builtin_bit_cast(bf16x8, *(const int4*)(Bp2 + ((size_t)kb * 128 + c1) * 8));
  }

  #pragma unroll
  for (int mf = 0; mf < 4; ++mf)
    #pragma unroll
    for (int nf = 0; nf < 2; ++nf) {
      int c = wave * 32 + nf * 16 + l16;
      #pragma unroll
      for (int rg = 0; rg < 4; ++rg) {
        int r = mf * 16 + wq * 4 + rg;
        float v = fmaxf(acc[mf][nf][rg], 0.0f);
        int lofs = (r * 256 + c * 2) ^ ((r & 7) << 4);
        *(unsigned short*)(Hlds + lofs) = f2bf(v);
      }
    }
  __syncthreads();

  f32x4 acc2[4][2];
  #pragma unroll
  for (int mf = 0; mf < 4; ++mf) {
    acc2[mf][0] = (f32x4){bias20, bias20, bias20, bias20};
    acc2[mf][1] = (f32x4){bias21, bias21, bias21, bias21};
  }
  #pragma unroll
  for (int ks = 0; ks < 4; ++ks)
    #pragma unroll
    for (int mf = 0; mf < 4; ++mf) {
      int r = mf * 16 + l16;
      int lofs = (r * 256 + ks * 64 + wq * 16) ^ ((r & 7) << 4);
      bf16x8 av = __builtin_bit_cast(bf16x8, *(const int4*)(Hlds + lofs));
      acc2[mf][0] = __builtin_amdgcn_mfma_f32_16x16x32_bf16(av, bf2r[ks][0], acc2[mf][0], 0, 0, 0);
      acc2[mf][1] = __builtin_amdgcn_mfma_f32_16x16x32_bf16(av, bf2r[ks][1], acc2[mf][1], 0, 0, 0);
    }

  #pragma unroll
  for (int mf = 0; mf < 4; ++mf)
    #pragma unroll
    for (int nf = 0; nf < 2; ++nf) {
      int c = wave * 32 + nf * 16 + l16;
      #pragma unroll
      for (int rg = 0; rg < 4; ++rg) {
        int r = mf * 16 + wq * 4 + rg;
        outp[(size_t)(eb + r) * 128 + c] = acc2[mf][nf][rg];
      }
    }
}

extern "C" void kernel_launch(void* const* d_in, const int* in_sizes, int n_in,
                              void* d_out, int out_size, void* d_ws, size_t ws_size,
                              hipStream_t stream) {
  const float* x  = (const float*)d_in[0];
  const float* ea = (const float*)d_in[1];
  const int* eidx = (const int*)d_in[2];
  const float* W1 = (const float*)d_in[3];
  const float* b1 = (const float*)d_in[4];
  const float* W2 = (const float*)d_in[5];
  const float* b2 = (const float*)d_in[6];
  float* outp = (float*)d_out;

  const int E = in_sizes[2] / 2;
  const int nnodes = in_sizes[0] / 128;
  const int ntiles = E / BM;

  unsigned short* Bp1 = (unsigned short*)d_ws;           // 64 KB
  unsigned short* Bp2 = Bp1 + 32768;                     // 32 KB
  unsigned short* xb  = (unsigned short*)((char*)d_ws + 98304);
  const size_t need = 98304 + (size_t)nnodes * 128 * 2;

  pack_w_kernel<<<192, 256, 0, stream>>>(W1, W2, Bp1, Bp2);

  if (ws_size >= need) {
    int n8 = nnodes * 128 / 8;
    convert_x_kernel<<<(n8 + 255) / 256, 256, 0, stream>>>(x, xb, n8);
    edge_nt<<<ntiles, 256, 0, stream>>>(xb, ea, eidx, W1, b1, b2, Bp1, Bp2, outp, E);
  } else {
    edge_fused_f32<<<ntiles, 256, 0, stream>>>(x, ea, eidx, W1, b1, b2, Bp1, Bp2, outp, E);
  }
}